// Round 3
// baseline (335.028 us; speedup 1.0000x reference)
//
#include <hip/hip_runtime.h>
#include <hip/hip_bf16.h>

// Problem constants (T,K,E,H,I) = (1024, 2, 8, 2048, 1024)
#define T_TOK 1024
#define KSEL  2
#define NEXP  8
#define HDIM  2048
#define IDIM  1024
#define TK    2048            // (token, slot) pairs; sum of expert counts == TK

#define BR 72                 // LDS B-tile row stride in bf16 elems (64 payload + 8 pad)
#define MT 3                  // M-tiles per expert (384 rows each); mt>0 inactive unless cnt>384

typedef float  f32x4  __attribute__((ext_vector_type(4)));
typedef __bf16 bf16x8 __attribute__((ext_vector_type(8)));
typedef __bf16 bf16x2 __attribute__((ext_vector_type(2)));

__device__ __forceinline__ unsigned short f2bf(float f) {
    union { float f; unsigned u; } v; v.f = f;
    unsigned r = (v.u >> 16) & 1u;               // round-to-nearest-even
    return (unsigned short)((v.u + 0x7fffu + r) >> 16);
}

__device__ __forceinline__ unsigned pk2bf(float lo, float hi) {
#if __has_builtin(__builtin_amdgcn_cvt_pk_bf16_f32)
    bf16x2 v = __builtin_amdgcn_cvt_pk_bf16_f32(lo, hi);
    union { bf16x2 v; unsigned u; } c; c.v = v;
    return c.u;
#else
    return (unsigned)f2bf(lo) | ((unsigned)f2bf(hi) << 16);
#endif
}

// Workgroup barrier WITHOUT the vmcnt(0) drain __syncthreads() emits.
// Only LDS ordering is needed across these barriers (ds_write -> ds_read);
// global prefetch loads live in registers and are ordered by the compiler's
// own per-dependency vmcnt(N) waits. With the 4-slab B prefetch this keeps
// ~4 slabs of loads in flight across barriers (T4: never drain vmcnt to 0).
__device__ __forceinline__ void wg_barrier_nodrain() {
    asm volatile("s_waitcnt lgkmcnt(0)" ::: "memory");
    __builtin_amdgcn_s_barrier();
}

// ---------------------------------------------------------------------------
// Kernel 1: prep = hidden fp32->bf16 (all blocks) + expert counting-sort
// (block 0 only). Grid 1024 x 256 covers T*H/8 = 262144 chunks exactly.
// ---------------------------------------------------------------------------
__global__ __launch_bounds__(256) void prep(
    const float* __restrict__ hidden, const int* __restrict__ sel,
    unsigned short* __restrict__ hid_bf, int* __restrict__ meta,
    int* __restrict__ pairs)
{
    const int t = blockIdx.x * 256 + threadIdx.x;
    {
        const float* s = hidden + (size_t)t * 8;
        float4 v0 = *(const float4*)s;
        float4 v1 = *(const float4*)(s + 4);
        uint4 o;
        o.x = pk2bf(v0.x, v0.y); o.y = pk2bf(v0.z, v0.w);
        o.z = pk2bf(v1.x, v1.y); o.w = pk2bf(v1.z, v1.w);
        *(uint4*)(hid_bf + (size_t)t * 8) = o;
    }
    if (blockIdx.x == 0) {
        __shared__ int lcnt[NEXP], lstart[NEXP], lfill[NEXP];
        const int tid = threadIdx.x;
        if (tid < NEXP) { lcnt[tid] = 0; lfill[tid] = 0; }
        __syncthreads();
        for (int i = tid; i < TK; i += 256) atomicAdd(&lcnt[sel[i]], 1);
        __syncthreads();
        if (tid == 0) {
            int s2 = 0;
            for (int e2 = 0; e2 < NEXP; ++e2) { lstart[e2] = s2; s2 += lcnt[e2]; }
        }
        __syncthreads();
        for (int i = tid; i < TK; i += 256) {
            int e2 = sel[i];
            pairs[lstart[e2] + atomicAdd(&lfill[e2], 1)] = i;   // i == t*K+k
        }
        if (tid < NEXP) { meta[tid] = lcnt[tid]; meta[NEXP + tid] = lstart[tid]; }
    }
}

// ---------------------------------------------------------------------------
// Kernel 2: gate_up GEMM + SiLU*up -> bf16 inter (packed rows).
// Block = 512 threads = 8 waves; wave w owns M rows [48w, 48w+48) -> 384 rows
// = full expert. N = 32 inter cols (64 weight rows: 32 gate + 32 up).
// B fp32 streamed once from HBM -> cvt in-reg -> LDS (triple-buffer LDS,
// FOUR-slab register prefetch: slab n lives in Br[n&3]; prologue must reload
// Br[0] with slab 4 after consuming slab 0 -- this was the round-2 bug).
// Barriers never drain vmcnt. Waves whose 48-row strip is beyond this
// expert's row count skip A-loads and MFMA. K-slab 64, NK=32.
// ---------------------------------------------------------------------------
__global__ __launch_bounds__(512, 2) void gemm1_gateup(
    const unsigned short* __restrict__ hid_bf, const float* __restrict__ gup,
    const int* __restrict__ meta, const int* __restrict__ pairs,
    unsigned short* __restrict__ inter)
{
    __shared__ __align__(16) unsigned short Bs[3][64 * BR];

    const int bx = blockIdx.x;
    const int e = bx & 7, nt = (bx >> 3) & 31, mt = bx >> 8;
    const int cnt = meta[e];
    const int m0 = mt * 384;
    if (m0 >= cnt) return;
    const int seg  = meta[8 + e];
    const int rows = cnt - m0;            // valid rows in this tile
    const int n0   = nt * 32;

    const int tid  = threadIdx.x;
    const int lane = tid & 63, w = tid >> 6;        // w in [0,8)
    const int quad = lane >> 4, l16 = lane & 15;
    const bool wact = (w * 48) < rows;              // wave has any live rows

    // B staging map (512 thr): thread = weight-row (tid>>3), k-chunk (tid&7)*8.
    const int brow = tid >> 3, bkc = (tid & 7) * 8;
    const int grow = (brow < 32) ? (n0 + brow) : (IDIM + n0 + (brow - 32));
    const float* __restrict__ bp =
        gup + (size_t)e * (2 * IDIM * HDIM) + (size_t)grow * HDIM + bkc;
    const int bofs = brow * BR + bkc;

    // A fragment base pointers: 3 m-tiles of 16 rows, lane row = l16.
    const unsigned short* ap[3];
    #pragma unroll
    for (int i = 0; i < 3; ++i) {
        int mr  = m0 + w * 48 + i * 16 + l16;
        int idx = seg + min(mr, cnt - 1);          // clamp (dup rows masked later)
        ap[i] = hid_bf + (size_t)(pairs[idx] >> 1) * HDIM + quad * 8;
    }

    f32x4 accg[3][2], accu[3][2];
    const f32x4 zero = {0.f, 0.f, 0.f, 0.f};
    #pragma unroll
    for (int i = 0; i < 3; ++i)
        #pragma unroll
        for (int j = 0; j < 2; ++j) { accg[i][j] = zero; accu[i][j] = zero; }

    float4 Br[4][2];
    bf16x8 afA[3][2], afB[3][2];

    auto loadB = [&](float4 (&br)[2], int s) {
        const float* p = bp + s * 64;
        br[0] = *(const float4*)p;
        br[1] = *(const float4*)(p + 4);
    };
    auto storeB = [&](const float4 (&br)[2], int buf) {
        uint4 o;
        o.x = pk2bf(br[0].x, br[0].y); o.y = pk2bf(br[0].z, br[0].w);
        o.z = pk2bf(br[1].x, br[1].y); o.w = pk2bf(br[1].z, br[1].w);
        *(uint4*)&Bs[buf][bofs] = o;
    };
    auto loadA = [&](bf16x8 (&af)[3][2], int s) {
        #pragma unroll
        for (int i = 0; i < 3; ++i)
            #pragma unroll
            for (int kk = 0; kk < 2; ++kk)
                af[i][kk] = *(const bf16x8*)(ap[i] + s * 64 + kk * 32);
    };
    auto compute = [&](const bf16x8 (&af)[3][2], int buf) {
        #pragma unroll
        for (int kk = 0; kk < 2; ++kk) {
            const int ko = kk * 32 + quad * 8;
            bf16x8 bg[2], bu[2];
            #pragma unroll
            for (int j = 0; j < 2; ++j) {
                bg[j] = *(const bf16x8*)&Bs[buf][(j * 16 + l16) * BR + ko];
                bu[j] = *(const bf16x8*)&Bs[buf][(32 + j * 16 + l16) * BR + ko];
            }
            #pragma unroll
            for (int i = 0; i < 3; ++i)
                #pragma unroll
                for (int j = 0; j < 2; ++j) {
                    accg[i][j] = __builtin_amdgcn_mfma_f32_16x16x32_bf16(af[i][kk], bg[j], accg[i][j], 0, 0, 0);
                    accu[i][j] = __builtin_amdgcn_mfma_f32_16x16x32_bf16(af[i][kk], bu[j], accu[i][j], 0, 0, 0);
                }
        }
    };

    const int NK = HDIM / 64;   // 32
    // Invariant: slab n occupies Br[n&3]. Prologue: consume slab 0 -> buf 0,
    // then keep slots filled with slabs 1,2,3,4 (slab 4 reload was missing
    // in round 2 -> stale data staged as slab 4).
    loadB(Br[0], 0);
    if (wact) loadA(afA, 0);
    storeB(Br[0], 0);
    loadB(Br[1], 1);
    loadB(Br[2], 2);
    loadB(Br[3], 3);
    loadB(Br[0], 4);
    wg_barrier_nodrain();       // prologue loads for slabs 1..4 stay in flight

    for (int s = 0; s < NK; s += 2) {
        // even half: Bs[s%3]=slab s ready; Br slots hold raw s+1..s+4
        if (wact) loadA(afB, s + 1);
        storeB(Br[(s + 1) & 3], (s + 1) % 3);
        if (s + 5 < NK) loadB(Br[(s + 1) & 3], s + 5);
        if (wact) compute(afA, s % 3);
        wg_barrier_nodrain();
        // odd half
        if (wact && s + 2 < NK) loadA(afA, s + 2);
        if (s + 2 < NK) storeB(Br[(s + 2) & 3], (s + 2) % 3);
        if (s + 6 < NK) loadB(Br[(s + 2) & 3], s + 6);
        if (wact) compute(afB, (s + 1) % 3);
        wg_barrier_nodrain();
    }

    // Epilogue: silu(gate)*up -> inter (packed rows, bf16).
    #pragma unroll
    for (int i = 0; i < 3; ++i) {
        #pragma unroll
        for (int r = 0; r < 4; ++r) {
            int mrow = w * 48 + i * 16 + quad * 4 + r;
            if (mrow < rows && mrow < 384) {
                size_t orow = (size_t)(seg + m0 + mrow) * IDIM;
                #pragma unroll
                for (int j = 0; j < 2; ++j) {
                    float g = accg[i][j][r], u = accu[i][j][r];
                    float sv = g * (1.f / (1.f + __expf(-g)));
                    inter[orow + n0 + j * 16 + l16] = f2bf(sv * u);
                }
            }
        }
    }
}

// ---------------------------------------------------------------------------
// Kernel 3: down-proj GEMM. Same skeleton: 512 thr, full-expert M (384) x 64
// H-cols, B = 64 down rows fp32 streamed once (4-slab register prefetch,
// slab n in Br[n&3], prologue reloads Br[0] with slab 4),
// A = inter direct from L2. K-slab 64, NK=16. Output fp32 -> out[pairs[p]].
// ---------------------------------------------------------------------------
__global__ __launch_bounds__(512, 2) void gemm2_down(
    const unsigned short* __restrict__ inter, const float* __restrict__ down,
    const int* __restrict__ meta, const int* __restrict__ pairs,
    float* __restrict__ out)
{
    __shared__ __align__(16) unsigned short Bs[3][64 * BR];

    const int bx = blockIdx.x;
    const int e = bx & 7, nt = (bx >> 3) & 31, mt = bx >> 8;
    const int cnt = meta[e];
    const int m0 = mt * 384;
    if (m0 >= cnt) return;
    const int seg  = meta[8 + e];
    const int rows = cnt - m0;
    const int n0   = nt * 64;

    const int tid  = threadIdx.x;
    const int lane = tid & 63, w = tid >> 6;
    const int quad = lane >> 4, l16 = lane & 15;
    const bool wact = (w * 48) < rows;

    const int brow = tid >> 3, bkc = (tid & 7) * 8;
    const float* __restrict__ bp =
        down + (size_t)e * (HDIM * IDIM) + (size_t)(n0 + brow) * IDIM + bkc;
    const int bofs = brow * BR + bkc;

    const unsigned short* ap[3];
    #pragma unroll
    for (int i = 0; i < 3; ++i) {
        int mr  = m0 + w * 48 + i * 16 + l16;
        int idx = seg + min(mr, cnt - 1);
        ap[i] = inter + (size_t)idx * IDIM + quad * 8;
    }

    f32x4 acc[3][4];
    const f32x4 zero = {0.f, 0.f, 0.f, 0.f};
    #pragma unroll
    for (int i = 0; i < 3; ++i)
        #pragma unroll
        for (int j = 0; j < 4; ++j) acc[i][j] = zero;

    float4 Br[4][2];
    bf16x8 afA[3][2], afB[3][2];

    auto loadB = [&](float4 (&br)[2], int s) {
        const float* p = bp + s * 64;
        br[0] = *(const float4*)p;
        br[1] = *(const float4*)(p + 4);
    };
    auto storeB = [&](const float4 (&br)[2], int buf) {
        uint4 o;
        o.x = pk2bf(br[0].x, br[0].y); o.y = pk2bf(br[0].z, br[0].w);
        o.z = pk2bf(br[1].x, br[1].y); o.w = pk2bf(br[1].z, br[1].w);
        *(uint4*)&Bs[buf][bofs] = o;
    };
    auto loadA = [&](bf16x8 (&af)[3][2], int s) {
        #pragma unroll
        for (int i = 0; i < 3; ++i)
            #pragma unroll
            for (int kk = 0; kk < 2; ++kk)
                af[i][kk] = *(const bf16x8*)(ap[i] + s * 64 + kk * 32);
    };
    auto compute = [&](const bf16x8 (&af)[3][2], int buf) {
        #pragma unroll
        for (int kk = 0; kk < 2; ++kk) {
            const int ko = kk * 32 + quad * 8;
            bf16x8 bf[4];
            #pragma unroll
            for (int j = 0; j < 4; ++j)
                bf[j] = *(const bf16x8*)&Bs[buf][(j * 16 + l16) * BR + ko];
            #pragma unroll
            for (int i = 0; i < 3; ++i)
                #pragma unroll
                for (int j = 0; j < 4; ++j)
                    acc[i][j] = __builtin_amdgcn_mfma_f32_16x16x32_bf16(af[i][kk], bf[j], acc[i][j], 0, 0, 0);
        }
    };

    const int NK = IDIM / 64;   // 16
    loadB(Br[0], 0);
    if (wact) loadA(afA, 0);
    storeB(Br[0], 0);
    loadB(Br[1], 1);
    loadB(Br[2], 2);
    loadB(Br[3], 3);
    loadB(Br[0], 4);
    wg_barrier_nodrain();

    for (int s = 0; s < NK; s += 2) {
        if (wact) loadA(afB, s + 1);
        storeB(Br[(s + 1) & 3], (s + 1) % 3);
        if (s + 5 < NK) loadB(Br[(s + 1) & 3], s + 5);
        if (wact) compute(afA, s % 3);
        wg_barrier_nodrain();
        if (wact && s + 2 < NK) loadA(afA, s + 2);
        if (s + 2 < NK) storeB(Br[(s + 2) & 3], (s + 2) % 3);
        if (s + 6 < NK) loadB(Br[(s + 2) & 3], s + 6);
        if (wact) compute(afB, (s + 1) % 3);
        wg_barrier_nodrain();
    }

    #pragma unroll
    for (int i = 0; i < 3; ++i) {
        #pragma unroll
        for (int r = 0; r < 4; ++r) {
            int mrow = w * 48 + i * 16 + quad * 4 + r;
            if (mrow < rows && mrow < 384) {
                int p = pairs[seg + m0 + mrow];          // == t*K+k = out row
                size_t ob = (size_t)p * HDIM + n0 + l16;
                #pragma unroll
                for (int j = 0; j < 4; ++j)
                    out[ob + j * 16] = acc[i][j][r];
            }
        }
    }
}

// ---------------------------------------------------------------------------
extern "C" void kernel_launch(void* const* d_in, const int* in_sizes, int n_in,
                              void* d_out, int out_size, void* d_ws, size_t ws_size,
                              hipStream_t stream) {
    const float* hidden = (const float*)d_in[0];   // (T, H) fp32
    const int*   sel    = (const int*)  d_in[1];   // (T, K) int32
    const float* gup    = (const float*)d_in[2];   // (E, 2I, H) fp32
    const float* down   = (const float*)d_in[3];   // (E, H, I) fp32
    float* out = (float*)d_out;                    // (T, K, H) fp32

    // ws: meta 16 ints | pairs 2048 ints | inter bf16 2048x1024 (4 MB)
    //     | hid_bf bf16 1024x2048 (4 MB)   -- total ~8.1 MB
    char* ws = (char*)d_ws;
    int* meta  = (int*)ws;
    int* pairs = meta + 16;
    unsigned short* inter  = (unsigned short*)(ws + 16384);
    unsigned short* hid_bf = inter + (size_t)TK * IDIM;

    prep<<<T_TOK * HDIM / 8 / 256, 256, 0, stream>>>(hidden, sel, hid_bf, meta, pairs);
    gemm1_gateup<<<MT * 32 * 8, 512, 0, stream>>>(hid_bf, gup, meta, pairs, inter);
    gemm2_down  <<<MT * 32 * 8, 512, 0, stream>>>(inter, down, meta, pairs, out);
}

// Round 4
// 293.746 us; speedup vs baseline: 1.1405x; 1.1405x over previous
//
#include <hip/hip_runtime.h>
#include <hip/hip_bf16.h>

// Problem constants (T,K,E,H,I) = (1024, 2, 8, 2048, 1024)
#define T_TOK 1024
#define KSEL  2
#define NEXP  8
#define HDIM  2048
#define IDIM  1024
#define TK    2048            // (token, slot) pairs; sum of expert counts == TK

#define BR 72                 // LDS B-tile row stride in bf16 elems (64 payload + 8 pad)
#define MT 3                  // M-tiles per expert (384 rows each); mt>0 inactive unless cnt>384

typedef float  f32x4  __attribute__((ext_vector_type(4)));
typedef __bf16 bf16x8 __attribute__((ext_vector_type(8)));
typedef __bf16 bf16x2 __attribute__((ext_vector_type(2)));

__device__ __forceinline__ unsigned short f2bf(float f) {
    union { float f; unsigned u; } v; v.f = f;
    unsigned r = (v.u >> 16) & 1u;               // round-to-nearest-even
    return (unsigned short)((v.u + 0x7fffu + r) >> 16);
}

__device__ __forceinline__ unsigned pk2bf(float lo, float hi) {
#if __has_builtin(__builtin_amdgcn_cvt_pk_bf16_f32)
    bf16x2 v = __builtin_amdgcn_cvt_pk_bf16_f32(lo, hi);
    union { bf16x2 v; unsigned u; } c; c.v = v;
    return c.u;
#else
    return (unsigned)f2bf(lo) | ((unsigned)f2bf(hi) << 16);
#endif
}

// Workgroup barrier WITHOUT the vmcnt(0) drain __syncthreads() emits.
// Only LDS ordering is needed across these barriers (ds_write -> ds_read);
// global prefetch loads live in registers and are ordered by the compiler's
// own per-dependency vmcnt(N) waits. With the 4-slab B prefetch this keeps
// ~4 slabs of loads in flight across barriers (T4: never drain vmcnt to 0).
__device__ __forceinline__ void wg_barrier_nodrain() {
    asm volatile("s_waitcnt lgkmcnt(0)" ::: "memory");
    __builtin_amdgcn_s_barrier();
}

// ---------------------------------------------------------------------------
// Kernel 1: prep = hidden fp32->bf16 (all blocks) + expert counting-sort
// (block 0 only). Grid 1024 x 256 covers T*H/8 = 262144 chunks exactly.
// ---------------------------------------------------------------------------
__global__ __launch_bounds__(256) void prep(
    const float* __restrict__ hidden, const int* __restrict__ sel,
    unsigned short* __restrict__ hid_bf, int* __restrict__ meta,
    int* __restrict__ pairs)
{
    const int t = blockIdx.x * 256 + threadIdx.x;
    {
        const float* s = hidden + (size_t)t * 8;
        float4 v0 = *(const float4*)s;
        float4 v1 = *(const float4*)(s + 4);
        uint4 o;
        o.x = pk2bf(v0.x, v0.y); o.y = pk2bf(v0.z, v0.w);
        o.z = pk2bf(v1.x, v1.y); o.w = pk2bf(v1.z, v1.w);
        *(uint4*)(hid_bf + (size_t)t * 8) = o;
    }
    if (blockIdx.x == 0) {
        __shared__ int lcnt[NEXP], lstart[NEXP], lfill[NEXP];
        const int tid = threadIdx.x;
        if (tid < NEXP) { lcnt[tid] = 0; lfill[tid] = 0; }
        __syncthreads();
        for (int i = tid; i < TK; i += 256) atomicAdd(&lcnt[sel[i]], 1);
        __syncthreads();
        if (tid == 0) {
            int s2 = 0;
            for (int e2 = 0; e2 < NEXP; ++e2) { lstart[e2] = s2; s2 += lcnt[e2]; }
        }
        __syncthreads();
        for (int i = tid; i < TK; i += 256) {
            int e2 = sel[i];
            pairs[lstart[e2] + atomicAdd(&lfill[e2], 1)] = i;   // i == t*K+k
        }
        if (tid < NEXP) { meta[tid] = lcnt[tid]; meta[NEXP + tid] = lstart[tid]; }
    }
}

// ---------------------------------------------------------------------------
// Kernel 2: gate_up GEMM + SiLU*up -> bf16 inter (packed rows).
// Block = 512 threads = 8 waves; wave w owns M rows [48w, 48w+48) -> 384 rows
// = full expert. N = 32 inter cols (64 weight rows: 32 gate + 32 up).
// B fp32 streamed once from HBM -> cvt in-reg -> LDS. FOUR-slab register
// prefetch with FULLY STATIC indexing: named slots Br0_..Br3_ (slab n ->
// slot n&3) and 4 LDS buffers (buf n&3), loop hand-unrolled x4. (Round-3
// bug: runtime-indexed Br[(s+1)&3] put the array in scratch -> 129 MB of
// HBM scratch traffic, rule #20.) Barriers never drain vmcnt. K-slab 64.
// ---------------------------------------------------------------------------
__global__ __launch_bounds__(512, 2) void gemm1_gateup(
    const unsigned short* __restrict__ hid_bf, const float* __restrict__ gup,
    const int* __restrict__ meta, const int* __restrict__ pairs,
    unsigned short* __restrict__ inter)
{
    __shared__ __align__(16) unsigned short Bs[4][64 * BR];

    const int bx = blockIdx.x;
    const int e = bx & 7, nt = (bx >> 3) & 31, mt = bx >> 8;
    const int cnt = meta[e];
    const int m0 = mt * 384;
    if (m0 >= cnt) return;
    const int seg  = meta[8 + e];
    const int rows = cnt - m0;            // valid rows in this tile
    const int n0   = nt * 32;

    const int tid  = threadIdx.x;
    const int lane = tid & 63, w = tid >> 6;        // w in [0,8)
    const int quad = lane >> 4, l16 = lane & 15;
    const bool wact = (w * 48) < rows;              // wave has any live rows

    // B staging map (512 thr): thread = weight-row (tid>>3), k-chunk (tid&7)*8.
    const int brow = tid >> 3, bkc = (tid & 7) * 8;
    const int grow = (brow < 32) ? (n0 + brow) : (IDIM + n0 + (brow - 32));
    const float* __restrict__ bp =
        gup + (size_t)e * (2 * IDIM * HDIM) + (size_t)grow * HDIM + bkc;
    const int bofs = brow * BR + bkc;

    // A fragment base pointers: 3 m-tiles of 16 rows, lane row = l16.
    const unsigned short* ap[3];
    #pragma unroll
    for (int i = 0; i < 3; ++i) {
        int mr  = m0 + w * 48 + i * 16 + l16;
        int idx = seg + min(mr, cnt - 1);          // clamp (dup rows masked later)
        ap[i] = hid_bf + (size_t)(pairs[idx] >> 1) * HDIM + quad * 8;
    }

    f32x4 accg[3][2], accu[3][2];
    const f32x4 zero = {0.f, 0.f, 0.f, 0.f};
    #pragma unroll
    for (int i = 0; i < 3; ++i)
        #pragma unroll
        for (int j = 0; j < 2; ++j) { accg[i][j] = zero; accu[i][j] = zero; }

    float4 Br0_[2], Br1_[2], Br2_[2], Br3_[2];     // named -> registers
    bf16x8 afX[3][2], afY[3][2];

    auto loadB = [&](float4 (&br)[2], int s) {
        const float* p = bp + s * 64;
        br[0] = *(const float4*)p;
        br[1] = *(const float4*)(p + 4);
    };
    auto storeB = [&](const float4 (&br)[2], int buf) {
        uint4 o;
        o.x = pk2bf(br[0].x, br[0].y); o.y = pk2bf(br[0].z, br[0].w);
        o.z = pk2bf(br[1].x, br[1].y); o.w = pk2bf(br[1].z, br[1].w);
        *(uint4*)&Bs[buf][bofs] = o;
    };
    auto loadA = [&](bf16x8 (&af)[3][2], int s) {
        #pragma unroll
        for (int i = 0; i < 3; ++i)
            #pragma unroll
            for (int kk = 0; kk < 2; ++kk)
                af[i][kk] = *(const bf16x8*)(ap[i] + s * 64 + kk * 32);
    };
    auto compute = [&](const bf16x8 (&af)[3][2], int buf) {
        #pragma unroll
        for (int kk = 0; kk < 2; ++kk) {
            const int ko = kk * 32 + quad * 8;
            bf16x8 bg[2], bu[2];
            #pragma unroll
            for (int j = 0; j < 2; ++j) {
                bg[j] = *(const bf16x8*)&Bs[buf][(j * 16 + l16) * BR + ko];
                bu[j] = *(const bf16x8*)&Bs[buf][(32 + j * 16 + l16) * BR + ko];
            }
            #pragma unroll
            for (int i = 0; i < 3; ++i)
                #pragma unroll
                for (int j = 0; j < 2; ++j) {
                    accg[i][j] = __builtin_amdgcn_mfma_f32_16x16x32_bf16(af[i][kk], bg[j], accg[i][j], 0, 0, 0);
                    accu[i][j] = __builtin_amdgcn_mfma_f32_16x16x32_bf16(af[i][kk], bu[j], accu[i][j], 0, 0, 0);
                }
        }
    };

    const int NK = HDIM / 64;   // 32 (divisible by 4)
    // Prologue: slab n -> slot n&3; stage slab 0 into buf 0; slot 0 refilled
    // with slab 4 (same-thread reg dataflow orders storeB before the reload).
    loadB(Br0_, 0);
    if (wact) loadA(afX, 0);
    storeB(Br0_, 0);
    loadB(Br1_, 1);
    loadB(Br2_, 2);
    loadB(Br3_, 3);
    loadB(Br0_, 4);
    wg_barrier_nodrain();       // prologue loads for slabs 1..4 stay in flight

    for (int s = 0; s < NK; s += 4) {
        // k=0: compute slab s (buf0, afX); stage s+1; refill slot1 with s+5
        if (wact) loadA(afY, s + 1);
        storeB(Br1_, 1);
        if (s + 5 < NK) loadB(Br1_, s + 5);
        if (wact) compute(afX, 0);
        wg_barrier_nodrain();
        // k=1: compute slab s+1 (buf1, afY); stage s+2; refill slot2 with s+6
        if (wact) loadA(afX, s + 2);
        storeB(Br2_, 2);
        if (s + 6 < NK) loadB(Br2_, s + 6);
        if (wact) compute(afY, 1);
        wg_barrier_nodrain();
        // k=2: compute slab s+2 (buf2, afX); stage s+3; refill slot3 with s+7
        if (wact) loadA(afY, s + 3);
        storeB(Br3_, 3);
        if (s + 7 < NK) loadB(Br3_, s + 7);
        if (wact) compute(afX, 2);
        wg_barrier_nodrain();
        // k=3: compute slab s+3 (buf3, afY); stage s+4; refill slot0 with s+8
        if (wact && s + 4 < NK) loadA(afX, s + 4);
        if (s + 4 < NK) storeB(Br0_, 0);
        if (s + 8 < NK) loadB(Br0_, s + 8);
        if (wact) compute(afY, 3);
        wg_barrier_nodrain();
    }

    // Epilogue: silu(gate)*up -> inter (packed rows, bf16).
    #pragma unroll
    for (int i = 0; i < 3; ++i) {
        #pragma unroll
        for (int r = 0; r < 4; ++r) {
            int mrow = w * 48 + i * 16 + quad * 4 + r;
            if (mrow < rows && mrow < 384) {
                size_t orow = (size_t)(seg + m0 + mrow) * IDIM;
                #pragma unroll
                for (int j = 0; j < 2; ++j) {
                    float g = accg[i][j][r], u = accu[i][j][r];
                    float sv = g * (1.f / (1.f + __expf(-g)));
                    inter[orow + n0 + j * 16 + l16] = f2bf(sv * u);
                }
            }
        }
    }
}

// ---------------------------------------------------------------------------
// Kernel 3: down-proj GEMM. Same skeleton: 512 thr, full-expert M (384) x 64
// H-cols, B = 64 down rows fp32 streamed once. Static 4-slot / 4-buf
// schedule identical to gemm1. K-slab 64, NK=16. Output fp32 -> out[pairs].
// ---------------------------------------------------------------------------
__global__ __launch_bounds__(512, 2) void gemm2_down(
    const unsigned short* __restrict__ inter, const float* __restrict__ down,
    const int* __restrict__ meta, const int* __restrict__ pairs,
    float* __restrict__ out)
{
    __shared__ __align__(16) unsigned short Bs[4][64 * BR];

    const int bx = blockIdx.x;
    const int e = bx & 7, nt = (bx >> 3) & 31, mt = bx >> 8;
    const int cnt = meta[e];
    const int m0 = mt * 384;
    if (m0 >= cnt) return;
    const int seg  = meta[8 + e];
    const int rows = cnt - m0;
    const int n0   = nt * 64;

    const int tid  = threadIdx.x;
    const int lane = tid & 63, w = tid >> 6;
    const int quad = lane >> 4, l16 = lane & 15;
    const bool wact = (w * 48) < rows;

    const int brow = tid >> 3, bkc = (tid & 7) * 8;
    const float* __restrict__ bp =
        down + (size_t)e * (HDIM * IDIM) + (size_t)(n0 + brow) * IDIM + bkc;
    const int bofs = brow * BR + bkc;

    const unsigned short* ap[3];
    #pragma unroll
    for (int i = 0; i < 3; ++i) {
        int mr  = m0 + w * 48 + i * 16 + l16;
        int idx = seg + min(mr, cnt - 1);
        ap[i] = inter + (size_t)idx * IDIM + quad * 8;
    }

    f32x4 acc[3][4];
    const f32x4 zero = {0.f, 0.f, 0.f, 0.f};
    #pragma unroll
    for (int i = 0; i < 3; ++i)
        #pragma unroll
        for (int j = 0; j < 4; ++j) acc[i][j] = zero;

    float4 Br0_[2], Br1_[2], Br2_[2], Br3_[2];
    bf16x8 afX[3][2], afY[3][2];

    auto loadB = [&](float4 (&br)[2], int s) {
        const float* p = bp + s * 64;
        br[0] = *(const float4*)p;
        br[1] = *(const float4*)(p + 4);
    };
    auto storeB = [&](const float4 (&br)[2], int buf) {
        uint4 o;
        o.x = pk2bf(br[0].x, br[0].y); o.y = pk2bf(br[0].z, br[0].w);
        o.z = pk2bf(br[1].x, br[1].y); o.w = pk2bf(br[1].z, br[1].w);
        *(uint4*)&Bs[buf][bofs] = o;
    };
    auto loadA = [&](bf16x8 (&af)[3][2], int s) {
        #pragma unroll
        for (int i = 0; i < 3; ++i)
            #pragma unroll
            for (int kk = 0; kk < 2; ++kk)
                af[i][kk] = *(const bf16x8*)(ap[i] + s * 64 + kk * 32);
    };
    auto compute = [&](const bf16x8 (&af)[3][2], int buf) {
        #pragma unroll
        for (int kk = 0; kk < 2; ++kk) {
            const int ko = kk * 32 + quad * 8;
            bf16x8 bf[4];
            #pragma unroll
            for (int j = 0; j < 4; ++j)
                bf[j] = *(const bf16x8*)&Bs[buf][(j * 16 + l16) * BR + ko];
            #pragma unroll
            for (int i = 0; i < 3; ++i)
                #pragma unroll
                for (int j = 0; j < 4; ++j)
                    acc[i][j] = __builtin_amdgcn_mfma_f32_16x16x32_bf16(af[i][kk], bf[j], acc[i][j], 0, 0, 0);
        }
    };

    const int NK = IDIM / 64;   // 16 (divisible by 4)
    loadB(Br0_, 0);
    if (wact) loadA(afX, 0);
    storeB(Br0_, 0);
    loadB(Br1_, 1);
    loadB(Br2_, 2);
    loadB(Br3_, 3);
    loadB(Br0_, 4);
    wg_barrier_nodrain();

    for (int s = 0; s < NK; s += 4) {
        if (wact) loadA(afY, s + 1);
        storeB(Br1_, 1);
        if (s + 5 < NK) loadB(Br1_, s + 5);
        if (wact) compute(afX, 0);
        wg_barrier_nodrain();

        if (wact) loadA(afX, s + 2);
        storeB(Br2_, 2);
        if (s + 6 < NK) loadB(Br2_, s + 6);
        if (wact) compute(afY, 1);
        wg_barrier_nodrain();

        if (wact) loadA(afY, s + 3);
        storeB(Br3_, 3);
        if (s + 7 < NK) loadB(Br3_, s + 7);
        if (wact) compute(afX, 2);
        wg_barrier_nodrain();

        if (wact && s + 4 < NK) loadA(afX, s + 4);
        if (s + 4 < NK) storeB(Br0_, 0);
        if (s + 8 < NK) loadB(Br0_, s + 8);
        if (wact) compute(afY, 3);
        wg_barrier_nodrain();
    }

    #pragma unroll
    for (int i = 0; i < 3; ++i) {
        #pragma unroll
        for (int r = 0; r < 4; ++r) {
            int mrow = w * 48 + i * 16 + quad * 4 + r;
            if (mrow < rows && mrow < 384) {
                int p = pairs[seg + m0 + mrow];          // == t*K+k = out row
                size_t ob = (size_t)p * HDIM + n0 + l16;
                #pragma unroll
                for (int j = 0; j < 4; ++j)
                    out[ob + j * 16] = acc[i][j][r];
            }
        }
    }
}

// ---------------------------------------------------------------------------
extern "C" void kernel_launch(void* const* d_in, const int* in_sizes, int n_in,
                              void* d_out, int out_size, void* d_ws, size_t ws_size,
                              hipStream_t stream) {
    const float* hidden = (const float*)d_in[0];   // (T, H) fp32
    const int*   sel    = (const int*)  d_in[1];   // (T, K) int32
    const float* gup    = (const float*)d_in[2];   // (E, 2I, H) fp32
    const float* down   = (const float*)d_in[3];   // (E, H, I) fp32
    float* out = (float*)d_out;                    // (T, K, H) fp32

    // ws: meta 16 ints | pairs 2048 ints | inter bf16 2048x1024 (4 MB)
    //     | hid_bf bf16 1024x2048 (4 MB)   -- total ~8.1 MB
    char* ws = (char*)d_ws;
    int* meta  = (int*)ws;
    int* pairs = meta + 16;
    unsigned short* inter  = (unsigned short*)(ws + 16384);
    unsigned short* hid_bf = inter + (size_t)TK * IDIM;

    prep<<<T_TOK * HDIM / 8 / 256, 256, 0, stream>>>(hidden, sel, hid_bf, meta, pairs);
    gemm1_gateup<<<MT * 32 * 8, 512, 0, stream>>>(hid_bf, gup, meta, pairs, inter);
    gemm2_down  <<<MT * 32 * 8, 512, 0, stream>>>(inter, down, meta, pairs, out);
}

// Round 5
// 288.263 us; speedup vs baseline: 1.1622x; 1.0190x over previous
//
#include <hip/hip_runtime.h>
#include <hip/hip_bf16.h>

// Problem constants (T,K,E,H,I) = (1024, 2, 8, 2048, 1024)
#define T_TOK 1024
#define KSEL  2
#define NEXP  8
#define HDIM  2048
#define IDIM  1024
#define TK    2048            // (token, slot) pairs; sum of expert counts == TK

#define BR 72                 // LDS B-tile row stride in bf16 elems (64 payload + 8 pad)
#define MT 3                  // M-tiles per expert (384 rows each); mt>0 inactive unless cnt>384

typedef float  f32x4  __attribute__((ext_vector_type(4)));
typedef __bf16 bf16x8 __attribute__((ext_vector_type(8)));
typedef __bf16 bf16x2 __attribute__((ext_vector_type(2)));

__device__ __forceinline__ unsigned short f2bf(float f) {
    union { float f; unsigned u; } v; v.f = f;
    unsigned r = (v.u >> 16) & 1u;               // round-to-nearest-even
    return (unsigned short)((v.u + 0x7fffu + r) >> 16);
}

__device__ __forceinline__ unsigned pk2bf(float lo, float hi) {
#if __has_builtin(__builtin_amdgcn_cvt_pk_bf16_f32)
    bf16x2 v = __builtin_amdgcn_cvt_pk_bf16_f32(lo, hi);
    union { bf16x2 v; unsigned u; } c; c.v = v;
    return c.u;
#else
    return (unsigned)f2bf(lo) | ((unsigned)f2bf(hi) << 16);
#endif
}

// Workgroup barrier WITHOUT the vmcnt(0) drain __syncthreads() emits.
// Only LDS ordering is needed across these barriers (ds_write -> ds_read);
// global prefetch loads live in registers and are ordered by the compiler's
// own per-dependency vmcnt(N) waits.
__device__ __forceinline__ void wg_barrier_nodrain() {
    asm volatile("s_waitcnt lgkmcnt(0)" ::: "memory");
    __builtin_amdgcn_s_barrier();
}

// ---------------------------------------------------------------------------
// Kernel 1: prep = hidden fp32->bf16 (all blocks) + expert counting-sort
// (block 0 only). Grid 1024 x 256 covers T*H/8 = 262144 chunks exactly.
// ---------------------------------------------------------------------------
__global__ __launch_bounds__(256) void prep(
    const float* __restrict__ hidden, const int* __restrict__ sel,
    unsigned short* __restrict__ hid_bf, int* __restrict__ meta,
    int* __restrict__ pairs)
{
    const int t = blockIdx.x * 256 + threadIdx.x;
    {
        const float* s = hidden + (size_t)t * 8;
        float4 v0 = *(const float4*)s;
        float4 v1 = *(const float4*)(s + 4);
        uint4 o;
        o.x = pk2bf(v0.x, v0.y); o.y = pk2bf(v0.z, v0.w);
        o.z = pk2bf(v1.x, v1.y); o.w = pk2bf(v1.z, v1.w);
        *(uint4*)(hid_bf + (size_t)t * 8) = o;
    }
    if (blockIdx.x == 0) {
        __shared__ int lcnt[NEXP], lstart[NEXP], lfill[NEXP];
        const int tid = threadIdx.x;
        if (tid < NEXP) { lcnt[tid] = 0; lfill[tid] = 0; }
        __syncthreads();
        for (int i = tid; i < TK; i += 256) atomicAdd(&lcnt[sel[i]], 1);
        __syncthreads();
        if (tid == 0) {
            int s2 = 0;
            for (int e2 = 0; e2 < NEXP; ++e2) { lstart[e2] = s2; s2 += lcnt[e2]; }
        }
        __syncthreads();
        for (int i = tid; i < TK; i += 256) {
            int e2 = sel[i];
            pairs[lstart[e2] + atomicAdd(&lfill[e2], 1)] = i;   // i == t*K+k
        }
        if (tid < NEXP) { meta[tid] = lcnt[tid]; meta[NEXP + tid] = lstart[tid]; }
    }
}

// ---------------------------------------------------------------------------
// Kernel 2: gate_up GEMM + SiLU*up -> bf16 inter (packed rows).
// Block = 512 threads = 8 waves; wave w owns M rows [48w, 48w+48).
// N = 32 inter cols (64 weight rows: 32 gate + 32 up). B fp32 streamed once
// from HBM -> cvt in-reg -> LDS. Static 4-slot/4-buf pipeline (round-4).
// NEW: per-block K-SLAB ROTATION. All blocks marching through K-slabs in
// lockstep makes the whole chip fetch the same 256B-window mod 8KB at any
// instant (8KB row stride) -> HBM-channel hotspotting pinned gemm1 at 78us
// across 3 schedule variants. Logical slab i -> physical (i+phase)&31 with
// phase=(nt+e)&31: the 32 nt-blocks of each expert cover all 32 offsets
// simultaneously -> uniform channel load. K-sum is order-independent; A and
// B use the same logical->physical map so slabs stay matched.
// ---------------------------------------------------------------------------
__global__ __launch_bounds__(512, 2) void gemm1_gateup(
    const unsigned short* __restrict__ hid_bf, const float* __restrict__ gup,
    const int* __restrict__ meta, const int* __restrict__ pairs,
    unsigned short* __restrict__ inter)
{
    __shared__ __align__(16) unsigned short Bs[4][64 * BR];

    const int bx = blockIdx.x;
    const int e = bx & 7, nt = (bx >> 3) & 31, mt = bx >> 8;
    const int cnt = meta[e];
    const int m0 = mt * 384;
    if (m0 >= cnt) return;
    const int seg  = meta[8 + e];
    const int rows = cnt - m0;            // valid rows in this tile
    const int n0   = nt * 32;

    const int tid  = threadIdx.x;
    const int lane = tid & 63, w = tid >> 6;        // w in [0,8)
    const int quad = lane >> 4, l16 = lane & 15;
    const bool wact = (w * 48) < rows;              // wave has any live rows

    const int NK  = HDIM / 64;            // 32 (power of 2)
    const int NKM = NK - 1;
    const int phase = (nt + e) & NKM;     // per-block slab rotation

    // B staging map (512 thr): thread = weight-row (tid>>3), k-chunk (tid&7)*8.
    const int brow = tid >> 3, bkc = (tid & 7) * 8;
    const int grow = (brow < 32) ? (n0 + brow) : (IDIM + n0 + (brow - 32));
    const float* __restrict__ bp =
        gup + (size_t)e * (2 * IDIM * HDIM) + (size_t)grow * HDIM + bkc;
    const int bofs = brow * BR + bkc;

    // A fragment base pointers: 3 m-tiles of 16 rows, lane row = l16.
    const unsigned short* ap[3];
    #pragma unroll
    for (int i = 0; i < 3; ++i) {
        int mr  = m0 + w * 48 + i * 16 + l16;
        int idx = seg + min(mr, cnt - 1);          // clamp (dup rows masked later)
        ap[i] = hid_bf + (size_t)(pairs[idx] >> 1) * HDIM + quad * 8;
    }

    f32x4 accg[3][2], accu[3][2];
    const f32x4 zero = {0.f, 0.f, 0.f, 0.f};
    #pragma unroll
    for (int i = 0; i < 3; ++i)
        #pragma unroll
        for (int j = 0; j < 2; ++j) { accg[i][j] = zero; accu[i][j] = zero; }

    float4 Br0_[2], Br1_[2], Br2_[2], Br3_[2];     // named -> registers
    bf16x8 afX[3][2], afY[3][2];

    auto loadB = [&](float4 (&br)[2], int s) {
        const float* p = bp + ((s + phase) & NKM) * 64;
        br[0] = *(const float4*)p;
        br[1] = *(const float4*)(p + 4);
    };
    auto storeB = [&](const float4 (&br)[2], int buf) {
        uint4 o;
        o.x = pk2bf(br[0].x, br[0].y); o.y = pk2bf(br[0].z, br[0].w);
        o.z = pk2bf(br[1].x, br[1].y); o.w = pk2bf(br[1].z, br[1].w);
        *(uint4*)&Bs[buf][bofs] = o;
    };
    auto loadA = [&](bf16x8 (&af)[3][2], int s) {
        const int so = ((s + phase) & NKM) * 64;
        #pragma unroll
        for (int i = 0; i < 3; ++i)
            #pragma unroll
            for (int kk = 0; kk < 2; ++kk)
                af[i][kk] = *(const bf16x8*)(ap[i] + so + kk * 32);
    };
    auto compute = [&](const bf16x8 (&af)[3][2], int buf) {
        #pragma unroll
        for (int kk = 0; kk < 2; ++kk) {
            const int ko = kk * 32 + quad * 8;
            bf16x8 bg[2], bu[2];
            #pragma unroll
            for (int j = 0; j < 2; ++j) {
                bg[j] = *(const bf16x8*)&Bs[buf][(j * 16 + l16) * BR + ko];
                bu[j] = *(const bf16x8*)&Bs[buf][(32 + j * 16 + l16) * BR + ko];
            }
            #pragma unroll
            for (int i = 0; i < 3; ++i)
                #pragma unroll
                for (int j = 0; j < 2; ++j) {
                    accg[i][j] = __builtin_amdgcn_mfma_f32_16x16x32_bf16(af[i][kk], bg[j], accg[i][j], 0, 0, 0);
                    accu[i][j] = __builtin_amdgcn_mfma_f32_16x16x32_bf16(af[i][kk], bu[j], accu[i][j], 0, 0, 0);
                }
        }
    };

    // Prologue: logical slab n -> slot n&3; stage slab 0 into buf 0; slot 0
    // refilled with slab 4 (same-thread reg dataflow orders storeB first).
    loadB(Br0_, 0);
    if (wact) loadA(afX, 0);
    storeB(Br0_, 0);
    loadB(Br1_, 1);
    loadB(Br2_, 2);
    loadB(Br3_, 3);
    loadB(Br0_, 4);
    wg_barrier_nodrain();       // prologue loads for slabs 1..4 stay in flight

    for (int s = 0; s < NK; s += 4) {
        // k=0: compute slab s (buf0, afX); stage s+1; refill slot1 with s+5
        if (wact) loadA(afY, s + 1);
        storeB(Br1_, 1);
        if (s + 5 < NK) loadB(Br1_, s + 5);
        if (wact) compute(afX, 0);
        wg_barrier_nodrain();
        // k=1: compute slab s+1 (buf1, afY); stage s+2; refill slot2 with s+6
        if (wact) loadA(afX, s + 2);
        storeB(Br2_, 2);
        if (s + 6 < NK) loadB(Br2_, s + 6);
        if (wact) compute(afY, 1);
        wg_barrier_nodrain();
        // k=2: compute slab s+2 (buf2, afX); stage s+3; refill slot3 with s+7
        if (wact) loadA(afY, s + 3);
        storeB(Br3_, 3);
        if (s + 7 < NK) loadB(Br3_, s + 7);
        if (wact) compute(afX, 2);
        wg_barrier_nodrain();
        // k=3: compute slab s+3 (buf3, afY); stage s+4; refill slot0 with s+8
        if (wact && s + 4 < NK) loadA(afX, s + 4);
        if (s + 4 < NK) storeB(Br0_, 0);
        if (s + 8 < NK) loadB(Br0_, s + 8);
        if (wact) compute(afY, 3);
        wg_barrier_nodrain();
    }

    // Epilogue: silu(gate)*up -> inter (packed rows, bf16).
    #pragma unroll
    for (int i = 0; i < 3; ++i) {
        #pragma unroll
        for (int r = 0; r < 4; ++r) {
            int mrow = w * 48 + i * 16 + quad * 4 + r;
            if (mrow < rows && mrow < 384) {
                size_t orow = (size_t)(seg + m0 + mrow) * IDIM;
                #pragma unroll
                for (int j = 0; j < 2; ++j) {
                    float g = accg[i][j][r], u = accu[i][j][r];
                    float sv = g * (1.f / (1.f + __expf(-g)));
                    inter[orow + n0 + j * 16 + l16] = f2bf(sv * u);
                }
            }
        }
    }
}

// ---------------------------------------------------------------------------
// Kernel 3: down-proj GEMM. Same skeleton: 512 thr, full-expert M (384) x 64
// H-cols, B = 64 down rows fp32 streamed once. Static 4-slot/4-buf schedule
// identical to gemm1, with the same per-block K-slab rotation (NK=16,
// 4KB row stride -> same lockstep hotspot). Output fp32 -> out[pairs].
// ---------------------------------------------------------------------------
__global__ __launch_bounds__(512, 2) void gemm2_down(
    const unsigned short* __restrict__ inter, const float* __restrict__ down,
    const int* __restrict__ meta, const int* __restrict__ pairs,
    float* __restrict__ out)
{
    __shared__ __align__(16) unsigned short Bs[4][64 * BR];

    const int bx = blockIdx.x;
    const int e = bx & 7, nt = (bx >> 3) & 31, mt = bx >> 8;
    const int cnt = meta[e];
    const int m0 = mt * 384;
    if (m0 >= cnt) return;
    const int seg  = meta[8 + e];
    const int rows = cnt - m0;
    const int n0   = nt * 64;

    const int tid  = threadIdx.x;
    const int lane = tid & 63, w = tid >> 6;
    const int quad = lane >> 4, l16 = lane & 15;
    const bool wact = (w * 48) < rows;

    const int NK  = IDIM / 64;            // 16 (power of 2)
    const int NKM = NK - 1;
    const int phase = (nt + e) & NKM;

    const int brow = tid >> 3, bkc = (tid & 7) * 8;
    const float* __restrict__ bp =
        down + (size_t)e * (HDIM * IDIM) + (size_t)(n0 + brow) * IDIM + bkc;
    const int bofs = brow * BR + bkc;

    const unsigned short* ap[3];
    #pragma unroll
    for (int i = 0; i < 3; ++i) {
        int mr  = m0 + w * 48 + i * 16 + l16;
        int idx = seg + min(mr, cnt - 1);
        ap[i] = inter + (size_t)idx * IDIM + quad * 8;
    }

    f32x4 acc[3][4];
    const f32x4 zero = {0.f, 0.f, 0.f, 0.f};
    #pragma unroll
    for (int i = 0; i < 3; ++i)
        #pragma unroll
        for (int j = 0; j < 4; ++j) acc[i][j] = zero;

    float4 Br0_[2], Br1_[2], Br2_[2], Br3_[2];
    bf16x8 afX[3][2], afY[3][2];

    auto loadB = [&](float4 (&br)[2], int s) {
        const float* p = bp + ((s + phase) & NKM) * 64;
        br[0] = *(const float4*)p;
        br[1] = *(const float4*)(p + 4);
    };
    auto storeB = [&](const float4 (&br)[2], int buf) {
        uint4 o;
        o.x = pk2bf(br[0].x, br[0].y); o.y = pk2bf(br[0].z, br[0].w);
        o.z = pk2bf(br[1].x, br[1].y); o.w = pk2bf(br[1].z, br[1].w);
        *(uint4*)&Bs[buf][bofs] = o;
    };
    auto loadA = [&](bf16x8 (&af)[3][2], int s) {
        const int so = ((s + phase) & NKM) * 64;
        #pragma unroll
        for (int i = 0; i < 3; ++i)
            #pragma unroll
            for (int kk = 0; kk < 2; ++kk)
                af[i][kk] = *(const bf16x8*)(ap[i] + so + kk * 32);
    };
    auto compute = [&](const bf16x8 (&af)[3][2], int buf) {
        #pragma unroll
        for (int kk = 0; kk < 2; ++kk) {
            const int ko = kk * 32 + quad * 8;
            bf16x8 bf[4];
            #pragma unroll
            for (int j = 0; j < 4; ++j)
                bf[j] = *(const bf16x8*)&Bs[buf][(j * 16 + l16) * BR + ko];
            #pragma unroll
            for (int i = 0; i < 3; ++i)
                #pragma unroll
                for (int j = 0; j < 4; ++j)
                    acc[i][j] = __builtin_amdgcn_mfma_f32_16x16x32_bf16(af[i][kk], bf[j], acc[i][j], 0, 0, 0);
        }
    };

    loadB(Br0_, 0);
    if (wact) loadA(afX, 0);
    storeB(Br0_, 0);
    loadB(Br1_, 1);
    loadB(Br2_, 2);
    loadB(Br3_, 3);
    loadB(Br0_, 4);
    wg_barrier_nodrain();

    for (int s = 0; s < NK; s += 4) {
        if (wact) loadA(afY, s + 1);
        storeB(Br1_, 1);
        if (s + 5 < NK) loadB(Br1_, s + 5);
        if (wact) compute(afX, 0);
        wg_barrier_nodrain();

        if (wact) loadA(afX, s + 2);
        storeB(Br2_, 2);
        if (s + 6 < NK) loadB(Br2_, s + 6);
        if (wact) compute(afY, 1);
        wg_barrier_nodrain();

        if (wact) loadA(afY, s + 3);
        storeB(Br3_, 3);
        if (s + 7 < NK) loadB(Br3_, s + 7);
        if (wact) compute(afX, 2);
        wg_barrier_nodrain();

        if (wact && s + 4 < NK) loadA(afX, s + 4);
        if (s + 4 < NK) storeB(Br0_, 0);
        if (s + 8 < NK) loadB(Br0_, s + 8);
        if (wact) compute(afY, 3);
        wg_barrier_nodrain();
    }

    #pragma unroll
    for (int i = 0; i < 3; ++i) {
        #pragma unroll
        for (int r = 0; r < 4; ++r) {
            int mrow = w * 48 + i * 16 + quad * 4 + r;
            if (mrow < rows && mrow < 384) {
                int p = pairs[seg + m0 + mrow];          // == t*K+k = out row
                size_t ob = (size_t)p * HDIM + n0 + l16;
                #pragma unroll
                for (int j = 0; j < 4; ++j)
                    out[ob + j * 16] = acc[i][j][r];
            }
        }
    }
}

// ---------------------------------------------------------------------------
extern "C" void kernel_launch(void* const* d_in, const int* in_sizes, int n_in,
                              void* d_out, int out_size, void* d_ws, size_t ws_size,
                              hipStream_t stream) {
    const float* hidden = (const float*)d_in[0];   // (T, H) fp32
    const int*   sel    = (const int*)  d_in[1];   // (T, K) int32
    const float* gup    = (const float*)d_in[2];   // (E, 2I, H) fp32
    const float* down   = (const float*)d_in[3];   // (E, H, I) fp32
    float* out = (float*)d_out;                    // (T, K, H) fp32

    // ws: meta 16 ints | pairs 2048 ints | inter bf16 2048x1024 (4 MB)
    //     | hid_bf bf16 1024x2048 (4 MB)   -- total ~8.1 MB
    char* ws = (char*)d_ws;
    int* meta  = (int*)ws;
    int* pairs = meta + 16;
    unsigned short* inter  = (unsigned short*)(ws + 16384);
    unsigned short* hid_bf = inter + (size_t)TK * IDIM;

    prep<<<T_TOK * HDIM / 8 / 256, 256, 0, stream>>>(hidden, sel, hid_bf, meta, pairs);
    gemm1_gateup<<<MT * 32 * 8, 512, 0, stream>>>(hid_bf, gup, meta, pairs, inter);
    gemm2_down  <<<MT * 32 * 8, 512, 0, stream>>>(inter, down, meta, pairs, out);
}